// Round 1
// baseline (3171.959 us; speedup 1.0000x reference)
//
#include <hip/hip_runtime.h>
#include <stdint.h>

typedef __attribute__((ext_vector_type(8))) short bf16x8;
typedef __attribute__((ext_vector_type(4))) float f32x4;
typedef __attribute__((ext_vector_type(4))) unsigned int u32x4;

__device__ __forceinline__ unsigned short f2bf(float f) {
  unsigned int u = __float_as_uint(f);
  return (unsigned short)((u + 0x7fffu + ((u >> 16) & 1u)) >> 16);  // RNE
}

__device__ __forceinline__ void gload16(const void* g, void* l) {
  __builtin_amdgcn_global_load_lds((const __attribute__((address_space(1))) void*)g,
                                   (__attribute__((address_space(3))) void*)l, 16, 0, 0);
}

// ---------------------------------------------------------------- zero
__global__ void zero_k(u32x4* __restrict__ p, int n16) {
  int i = blockIdx.x * blockDim.x + threadIdx.x;
  int stride = gridDim.x * blockDim.x;
  u32x4 z = {0u, 0u, 0u, 0u};
  for (; i < n16; i += stride) p[i] = z;
}

// ------------------------------------------- fp32 NHWC -> padded bf16 NHWC
// dst layout: [8][H+2][W+2][256], halo = 0
__global__ void conv_in_k(const float* __restrict__ x, unsigned short* __restrict__ dst,
                          int H, int total) {
  int idx = blockIdx.x * 256 + threadIdx.x;
  if (idx >= total) return;
  const int W = H, Hp = H + 2, Wp = H + 2;
  int c8 = idx & 31;
  int rest = idx >> 5;            // (n*Hp + yp)*Wp + xp
  int xp = rest % Wp;
  int r2 = rest / Wp;
  int yp = r2 % Hp;
  int n = r2 / Hp;
  u32x4 o = {0u, 0u, 0u, 0u};
  int iy = yp - 1, ix = xp - 1;
  if ((unsigned)iy < (unsigned)H && (unsigned)ix < (unsigned)W) {
    const float* s = x + ((long)((n * H + iy) * W + ix) * 256 + c8 * 8);
    float4 a = *(const float4*)s;
    float4 b = *(const float4*)(s + 4);
    o.x = f2bf(a.x) | ((unsigned)f2bf(a.y) << 16);
    o.y = f2bf(a.z) | ((unsigned)f2bf(a.w) << 16);
    o.z = f2bf(b.x) | ((unsigned)f2bf(b.y) << 16);
    o.w = f2bf(b.z) | ((unsigned)f2bf(b.w) << 16);
  }
  *(u32x4*)(dst + (long)idx * 8) = o;
}

// ------------------------------- HWIO fp32 [2304][CoutReal] -> bf16 [CoutPad][2304]
__global__ void conv_w_k(const float* __restrict__ w, unsigned short* __restrict__ wT,
                         int CoutReal, int total) {
  int idx = blockIdx.x * 256 + threadIdx.x;
  if (idx >= total) return;
  int k8 = idx % 288;        // 2304/8
  int co = idx / 288;
  u32x4 o = {0u, 0u, 0u, 0u};
  if (co < CoutReal) {
    unsigned short v[8];
#pragma unroll
    for (int j = 0; j < 8; ++j)
      v[j] = f2bf(w[(long)(k8 * 8 + j) * CoutReal + co]);
    o.x = v[0] | ((unsigned)v[1] << 16);
    o.y = v[2] | ((unsigned)v[3] << 16);
    o.z = v[4] | ((unsigned)v[5] << 16);
    o.w = v[6] | ((unsigned)v[7] << 16);
  }
  *(u32x4*)(wT + (long)co * 2304 + k8 * 8) = o;
}

// ---------------------------------------------------------------- conv 3x3
// Implicit GEMM, m97 structure: 128x128 tile, BK=64, 4 waves of 4x4 16x16x32 frags.
// src: padded bf16 act. wT: [CoutPad][2304] bf16. FINAL: fp32 pixel-major out, no ReLU.
template<bool FINAL>
__global__ __launch_bounds__(256, 2)
void conv3x3_k(const unsigned short* __restrict__ src,
               const unsigned short* __restrict__ wT,
               const float* __restrict__ bias,
               unsigned short* __restrict__ dstAct,
               float* __restrict__ dstOut,
               int H, int lW, int lHW, int CoutReal)
{
  __shared__ char smem[32768];              // A: [0,16K) B: [16K,32K), [128][64] bf16 each
  const int tid = threadIdx.x;
  const int W = H, Hp = H + 2, Wp = H + 2;
  const int tileM = blockIdx.x * 128;
  const int tileN = blockIdx.y * 128;

  // staging addresses: g = i*256+tid -> row g>>3, 16B-part g&7 (XOR-swizzled on the
  // GLOBAL side; LDS dest stays linear — global_load_lds requirement)
  int aOff[4], bOff[4];
#pragma unroll
  for (int i = 0; i < 4; ++i) {
    int g = i * 256 + tid;
    int r = g >> 3;
    int psw = (g & 7) ^ (r & 7);
    int p = tileM + r;
    int n = p >> lHW;
    int y = (p >> lW) & (H - 1);
    int x = p & (W - 1);
    aOff[i] = ((n * Hp + y) * Wp + x) * 256 + psw * 8;   // tap (0,0) base, elements
    bOff[i] = (tileN + r) * 2304 + psw * 8;
  }

  const int lane = tid & 63;
  const int wv = tid >> 6;
  const int l15 = lane & 15;
  const int k8 = lane >> 4;
  const int moff = (wv >> 1) * 64;
  const int noff = (wv & 1) * 64;
  const int xorv = (l15 & 7) << 4;

  int aF[4], bF[4];                       // byte offsets for ks=0; ks=1 toggles bit 6
#pragma unroll
  for (int m = 0; m < 4; ++m)
    aF[m] = (((moff + m * 16 + l15) << 7) + (k8 << 4)) ^ xorv;
#pragma unroll
  for (int n = 0; n < 4; ++n)
    bF[n] = 16384 + ((((noff + n * 16 + l15) << 7) + (k8 << 4)) ^ xorv);

  f32x4 acc[4][4];
#pragma unroll
  for (int m = 0; m < 4; ++m)
#pragma unroll
    for (int n = 0; n < 4; ++n)
      acc[m][n] = (f32x4){0.f, 0.f, 0.f, 0.f};

  for (int tap = 0; tap < 9; ++tap) {
    const int ky = (tap * 11) >> 5;       // tap/3 for tap<9
    const int kx = tap - ky * 3;
    const int offA = (ky * Wp + kx) * 256;
    const int offB = tap * 256;
#pragma unroll
    for (int cc = 0; cc < 4; ++cc) {
      const int ccOff = cc * 64;
#pragma unroll
      for (int i = 0; i < 4; ++i)
        gload16(src + aOff[i] + offA + ccOff, smem + i * 4096 + tid * 16);
#pragma unroll
      for (int i = 0; i < 4; ++i)
        gload16(wT + bOff[i] + offB + ccOff, smem + 16384 + i * 4096 + tid * 16);
      __syncthreads();                    // compiler drains vmcnt before s_barrier
#pragma unroll
      for (int ks = 0; ks < 2; ++ks) {
        bf16x8 av[4], bv[4];
#pragma unroll
        for (int m = 0; m < 4; ++m) av[m] = *(const bf16x8*)(smem + (aF[m] ^ (ks << 6)));
#pragma unroll
        for (int n = 0; n < 4; ++n) bv[n] = *(const bf16x8*)(smem + (bF[n] ^ (ks << 6)));
#pragma unroll
        for (int m = 0; m < 4; ++m)
#pragma unroll
          for (int n = 0; n < 4; ++n)
            acc[m][n] = __builtin_amdgcn_mfma_f32_16x16x32_bf16(av[m], bv[n], acc[m][n], 0, 0, 0);
      }
      __syncthreads();                    // protect LDS before next stage
    }
  }

  // epilogue: C/D layout col=lane&15, row=(lane>>4)*4+reg (m89-verified)
#pragma unroll
  for (int n = 0; n < 4; ++n) {
    const int colG = tileN + noff + n * 16 + l15;
    float bv = 0.f;
    if (!FINAL || colG < CoutReal) bv = bias[colG];
#pragma unroll
    for (int m = 0; m < 4; ++m) {
#pragma unroll
      for (int r = 0; r < 4; ++r) {
        const int p = tileM + moff + m * 16 + (k8 << 2) + r;
        float v = acc[m][n][r] + bv;
        if (FINAL) {
          if (colG < CoutReal) dstOut[(long)p * CoutReal + colG] = v;
        } else {
          v = fmaxf(v, 0.f);
          const int n_img = p >> lHW;
          const int y = (p >> lW) & (H - 1);
          const int x = p & (W - 1);
          dstAct[((long)((n_img * Hp + y + 1) * Wp + x + 1)) * 256 + colG] = f2bf(v);
        }
      }
    }
  }
}

// ---------------------------------------------------------------- host
static void run_branch(const unsigned short* A, unsigned short* Am, unsigned short* B,
                       const unsigned short* wT, const float* bias,
                       const unsigned short* wTout, const float* biasOut,
                       int CoutReal, int CoutPad, float* out,
                       int H, int lW, int lHW, int M, hipStream_t stream) {
  dim3 blk(256);
  dim3 g1(M / 128, 2);
  conv3x3_k<false><<<g1, blk, 0, stream>>>(A, wT + 0L * 589824, bias + 0, B, nullptr, H, lW, lHW, 256);
  conv3x3_k<false><<<g1, blk, 0, stream>>>(B, wT + 1L * 589824, bias + 256, Am, nullptr, H, lW, lHW, 256);
  conv3x3_k<false><<<g1, blk, 0, stream>>>(Am, wT + 2L * 589824, bias + 512, B, nullptr, H, lW, lHW, 256);
  conv3x3_k<false><<<g1, blk, 0, stream>>>(B, wT + 3L * 589824, bias + 768, Am, nullptr, H, lW, lHW, 256);
  dim3 g2(M / 128, CoutPad / 128);
  conv3x3_k<true><<<g2, blk, 0, stream>>>(Am, wTout, biasOut, nullptr, out, H, lW, lHW, CoutReal);
}

extern "C" void kernel_launch(void* const* d_in, const int* in_sizes, int n_in,
                              void* d_out, int out_size, void* d_ws, size_t ws_size,
                              hipStream_t stream) {
  const float* x[3] = {(const float*)d_in[0], (const float*)d_in[1], (const float*)d_in[2]};
  const float* cls_w      = (const float*)d_in[3];
  const float* cls_b      = (const float*)d_in[4];
  const float* bbox_w     = (const float*)d_in[5];
  const float* bbox_b     = (const float*)d_in[6];
  const float* cls_out_w  = (const float*)d_in[7];
  const float* cls_out_b  = (const float*)d_in[8];
  const float* bbox_out_w = (const float*)d_in[9];
  const float* bbox_out_b = (const float*)d_in[10];
  float* out = (float*)d_out;

  // ws layout (bytes): bufA [0,69222400) bufB [69222400,138444800) weights after
  char* ws = (char*)d_ws;
  unsigned short* bufA = (unsigned short*)ws;
  unsigned short* bufB = (unsigned short*)(ws + 69222400);
  unsigned short* wt   = (unsigned short*)(ws + 138444800);
  unsigned short* wT_cls      = wt;                       // 4 * 256*2304
  unsigned short* wT_bbox     = wt + 4L * 589824;
  unsigned short* wT_cls_out  = wt + 8L * 589824;         // 768*2304
  unsigned short* wT_bbox_out = wT_cls_out + 1769472;     // 128*2304

  // ---- weight prep (every call: no cached state allowed)
  for (int i = 0; i < 4; ++i) {
    conv_w_k<<<288, 256, 0, stream>>>(cls_w  + (long)i * 589824, wT_cls  + (long)i * 589824, 256, 73728);
    conv_w_k<<<288, 256, 0, stream>>>(bbox_w + (long)i * 589824, wT_bbox + (long)i * 589824, 256, 73728);
  }
  conv_w_k<<<864, 256, 0, stream>>>(cls_out_w,  wT_cls_out,  720, 221184);
  conv_w_k<<<144, 256, 0, stream>>>(bbox_out_w, wT_bbox_out, 36, 36864);

  const int  Hs[3]   = {128, 64, 32};
  const int  lWs[3]  = {7, 6, 5};
  const int  lHWs[3] = {14, 12, 10};
  const long clsOff[3] = {0L, 94371840L, 117964800L};
  const long boxOff[3] = {123863040L, 128581632L, 129761280L};

  for (int lv = 0; lv < 3; ++lv) {
    const int H = Hs[lv], Hp = H + 2;
    const int M = 8 * H * H;
    const int paddedElems = 8 * Hp * Hp * 256;
    const int totalConv = 8 * Hp * Hp * 32;

    // zero bufB (halo must be 0; interiors get overwritten by convs)
    zero_k<<<2048, 256, 0, stream>>>((u32x4*)bufB, paddedElems / 8);

    // cls branch
    conv_in_k<<<(totalConv + 255) / 256, 256, 0, stream>>>(x[lv], bufA, H, totalConv);
    run_branch(bufA, bufA, bufB, wT_cls, cls_b, wT_cls_out, cls_out_b,
               720, 768, out + clsOff[lv], H, lWs[lv], lHWs[lv], M, stream);

    // bbox branch (re-convert input; cls chain overwrote bufA interior, halo intact)
    conv_in_k<<<(totalConv + 255) / 256, 256, 0, stream>>>(x[lv], bufA, H, totalConv);
    run_branch(bufA, bufA, bufB, wT_bbox, bbox_b, wT_bbox_out, bbox_out_b,
               36, 128, out + boxOff[lv], H, lWs[lv], lHWs[lv], M, stream);
  }
}